// Round 10
// baseline (186.698 us; speedup 1.0000x reference)
//
#include <hip/hip_runtime.h>
#include <math.h>

#define BS 2048   // B*S tokens
#define H  1024
#define E  8
#define F  512

typedef __attribute__((ext_vector_type(8))) short bf16x8;
typedef __attribute__((ext_vector_type(4))) float f32x4;
typedef unsigned short u16;
typedef unsigned int u32;

__device__ inline u16 f2bf(float f) {
    u32 u = __float_as_uint(f);
    return (u16)((u + 0x7fffu + ((u >> 16) & 1u)) >> 16);
}

// ws layout (bytes):
//        0: counters: [16..24) = per-expert gathered counts
//     4096: sel      int2[BS]   (expert id | valid<<8 | mismatch<<9 per slot)
//    20480: wsel     float2[BS]
//    36864: tok_list int[E*BS]
//   102400: w_list   float[E*BS]
//   167936: x_bf     u16[BS*H]            (4 MB)
//  4362240: gup_f    u16[E*1024*1024]     (16 MB) fragment-major bf16 (NB=64,KB=32)
// 21139456: down_f   u16[E*1024*512]      (8 MB)  fragment-major bf16 (NB=64,KB=16)
// 29528064: act      u16[4096*F]          (4 MB)  w-scaled silu(g)*u, bf16
//
// Fragment-major: frag(nb,kb) = 1KB; lane l holds B[n=nb*16+(l&15)][k=kb*32+(l>>4)*8+j]
// at frag_base + l*16B. One wave dwordx4 load = one coalesced MFMA B-operand.

// ---- K1: fused weight frag-format (blocks 0..3071) + router (blocks 3072..3583) ----
__global__ __launch_bounds__(256) void prep_router_kernel(
    const float* __restrict__ gup, const float* __restrict__ dwn,
    u16* __restrict__ gf, u16* __restrict__ df,
    const float* __restrict__ x, const float* __restrict__ gate_w,
    const int* __restrict__ tok_mod, const int* __restrict__ exp_mod,
    int2* __restrict__ sel_out, float2* __restrict__ w_out,
    u16* __restrict__ xb, float* __restrict__ out)
{
    int b = blockIdx.x;
    int tid = threadIdx.x;

    if (b < 3072) {
        // ---------- weight frag-format: fp32 [k][n] -> bf16 fragments ----------
        const float* src; u16* dst_base; int kt, nt, KB;
        if (b < 2048) {           // gup: e in [0,8), 16 k-tiles x 16 n-tiles, KB=32
            int e = b >> 8; int rem = b & 255; kt = rem >> 4; nt = rem & 15;
            src = gup + (size_t)e * 1048576; dst_base = gf + (size_t)e * 1048576; KB = 32;
        } else {                  // down: e in [0,8), 8 k-tiles x 16 n-tiles, KB=16
            int b2 = b - 2048; int e = b2 >> 7; int rem = b2 & 127; kt = rem >> 4; nt = rem & 15;
            src = dwn + (size_t)e * 524288; dst_base = df + (size_t)e * 524288; KB = 16;
        }
        int k0 = kt * 64, n0 = nt * 64;
        __shared__ float t[64][68];
        {
            int r = tid >> 2, c4 = tid & 3;
            const float* srow = src + (size_t)(k0 + r) * 1024 + n0 + c4 * 16;
#pragma unroll
            for (int i = 0; i < 4; i++) {
                float4 v = *(const float4*)(srow + i * 4);
                *(float4*)&t[r][c4 * 16 + i * 4] = v;
            }
        }
        __syncthreads();
        // 8 frags per 64x64 tile: fi = (nbi<<1)|kbi
        int fi = tid >> 5, lp = tid & 31;
        int nbi = fi >> 1, kbi = fi & 1;
        int nb = nt * 4 + nbi, kb = kt * 2 + kbi;
        u16* fb = dst_base + (((size_t)nb * KB + kb) << 9);
#pragma unroll
        for (int h = 0; h < 2; h++) {
            int l = lp * 2 + h;
            int nl = nbi * 16 + (l & 15);
            int kl = kbi * 32 + (l >> 4) * 8;
            u16 o[8];
#pragma unroll
            for (int j = 0; j < 8; j++) o[j] = f2bf(t[kl + j][nl]);
            uint4 q;
            q.x = (u32)o[0] | ((u32)o[1] << 16); q.y = (u32)o[2] | ((u32)o[3] << 16);
            q.z = (u32)o[4] | ((u32)o[5] << 16); q.w = (u32)o[6] | ((u32)o[7] << 16);
            *(uint4*)(fb + l * 8) = q;
        }
        return;
    }

    // ---------- router: one wave per token, 4 tokens per block ----------
    int wv = tid >> 6, lane = tid & 63;
    int token = (b - 3072) * 4 + wv;
    float4 z = make_float4(0.f, 0.f, 0.f, 0.f);
    float4* orow4 = (float4*)(out + (size_t)token * H);
#pragma unroll
    for (int i = 0; i < 4; i++) orow4[lane + 64 * i] = z;

    const float4* xr4 = (const float4*)(x + (size_t)token * H);
    const float4* gw4 = (const float4*)gate_w;
    float acc[E];
#pragma unroll
    for (int e = 0; e < E; e++) acc[e] = 0.f;
#pragma unroll
    for (int i = 0; i < 4; i++) {
        int idx = lane + 64 * i;
        float4 xv = xr4[idx];
        ushort4 pk;
        pk.x = f2bf(xv.x); pk.y = f2bf(xv.y); pk.z = f2bf(xv.z); pk.w = f2bf(xv.w);
        *(ushort4*)(xb + (size_t)token * H + idx * 4) = pk;
#pragma unroll
        for (int e = 0; e < E; e++) {
            float4 g = gw4[e * 256 + idx];
            acc[e] += xv.x * g.x + xv.y * g.y + xv.z * g.z + xv.w * g.w;
        }
    }
#pragma unroll
    for (int e = 0; e < E; e++) {
#pragma unroll
        for (int off = 32; off > 0; off >>= 1) acc[e] += __shfl_down(acc[e], off, 64);
    }
    if (lane == 0) {
        float m = acc[0];
#pragma unroll
        for (int e = 1; e < E; e++) m = fmaxf(m, acc[e]);
        float p[E]; float s = 0.f;
#pragma unroll
        for (int e = 0; e < E; e++) { p[e] = expf(acc[e] - m); s += p[e]; }
        float inv = 1.f / s;
#pragma unroll
        for (int e = 0; e < E; e++) p[e] *= inv;
        int i0 = 0; float p0 = p[0];
#pragma unroll
        for (int e = 1; e < E; e++) if (p[e] > p0) { p0 = p[e]; i0 = e; }
        int i1 = -1; float p1 = -1.f;
#pragma unroll
        for (int e = 0; e < E; e++) if (e != i0 && p[e] > p1) { p1 = p[e]; i1 = e; }
        float rs = 1.f / (p0 + p1);
        float w0 = p0 * rs, w1 = p1 * rs;
        int tm = tok_mod[token];
        int em0 = exp_mod[i0], em1 = exp_mod[i1];
        int v0 = (tm != 0) && (em0 != 0);
        int v1 = (tm != 0) && (em1 != 0);
        int mm0 = v0 && (tm * em0 == -1);
        int mm1 = v1 && (tm * em1 == -1);
        sel_out[token] = make_int2(i0 | (v0 << 8) | (mm0 << 9),
                                   i1 | (v1 << 8) | (mm1 << 9));
        w_out[token] = make_float2(w0, w1);
    }
}

// ---- K2: single-block finalize: reduce valid/mismatch, skip, renorm, gather ----
__global__ __launch_bounds__(1024) void finalize_kernel(
    const int* __restrict__ exp_mod, int* __restrict__ counters,
    const int2* __restrict__ sel_in, const float2* __restrict__ w_in,
    int* __restrict__ tok_list, float* __restrict__ w_list)
{
    __shared__ int vcnt[E], mcnt[E], gpos[E];
    int tid = threadIdx.x;
    if (tid < E) { vcnt[tid] = 0; mcnt[tid] = 0; gpos[tid] = 0; }
    __syncthreads();
#pragma unroll
    for (int h = 0; h < 2; h++) {
        int t = tid + h * 1024;
        int2 s = sel_in[t];
        int i0 = s.x & 7, i1 = s.y & 7;
        if (s.x & 256) atomicAdd(&vcnt[i0], 1);
        if (s.x & 512) atomicAdd(&mcnt[i0], 1);
        if (s.y & 256) atomicAdd(&vcnt[i1], 1);
        if (s.y & 512) atomicAdd(&mcnt[i1], 1);
    }
    __syncthreads();
    bool skip[E];
#pragma unroll
    for (int e = 0; e < E; e++)
        skip[e] = (vcnt[e] > 0) && (mcnt[e] == vcnt[e]) && (exp_mod[e] != 0);
#pragma unroll
    for (int h = 0; h < 2; h++) {
        int t = tid + h * 1024;
        int2 s = sel_in[t];
        int i0 = s.x & 7, i1 = s.y & 7;
        float2 w = w_in[t];
        float w0 = skip[i0] ? 0.f : w.x;
        float w1 = skip[i1] ? 0.f : w.y;
        float sm = w0 + w1;
        if (sm > 0.f) { float inv = 1.f / fmaxf(sm, 1e-9f); w0 *= inv; w1 *= inv; }
        if (w0 > 0.f) {
            int pos = atomicAdd(&gpos[i0], 1);
            tok_list[i0 * BS + pos] = t; w_list[i0 * BS + pos] = w0;
        }
        if (w1 > 0.f) {
            int pos = atomicAdd(&gpos[i1], 1);
            tok_list[i1 * BS + pos] = t; w_list[i1 * BS + pos] = w1;
        }
    }
    __syncthreads();
    if (tid < E) counters[16 + tid] = gpos[tid];
}

// ---- K3: gu MFMA, barrier-free register pipeline.
//      Block: 4 waves; wave w owns rows t0+w*16..+16, cols f0..f0+64 (g) paired with u.
//      A-frag: per-lane gather from x_bf (L2-hot). B-frag: coalesced 1KB from gup_f.
__global__ __launch_bounds__(256) void gu_mfma_kernel(
    const u16* __restrict__ xb, const u16* __restrict__ gup_f,
    const int* __restrict__ counters, const int* __restrict__ tok_list,
    const float* __restrict__ w_list, u16* __restrict__ act)
{
    int e = blockIdx.z;
    int n = counters[16 + e];
    int t0 = blockIdx.y * 64;
    if (t0 >= n) return;
    int f0 = blockIdx.x * 64;   // 8 f-groups of 64 g-cols (+ paired u) -> covers F=512
    int base = 0;
#pragma unroll
    for (int i = 0; i < E; i++) if (i < e) base += counters[16 + i];

    int tid = threadIdx.x;
    int wv = tid >> 6, lane = tid & 63;
    int l16 = lane & 15, quad = lane >> 4;

    // A fragment: lane row = t0 + wv*16 + l16, k-chunk = quad
    int Ra = min(t0 + wv * 16 + l16, n - 1);
    int tok = tok_list[e * BS + Ra];
    const u16* ap = xb + (size_t)tok * H + quad * 8;
    // B fragments: j 0..3 = g cols f0+j*16, j 4..7 = u cols 512+f0+(j-4)*16
    const u16* bp[8];
#pragma unroll
    for (int j = 0; j < 8; j++) {
        int nbj = (j < 4) ? ((f0 >> 4) + j) : (32 + (f0 >> 4) + (j - 4));
        bp[j] = gup_f + ((size_t)e << 20) + ((size_t)nbj << 14) + (size_t)lane * 8;
    }

    f32x4 acc[8];
#pragma unroll
    for (int j = 0; j < 8; j++) acc[j] = (f32x4){0.f, 0.f, 0.f, 0.f};

    bf16x8 aC = *(const bf16x8*)ap;
    bf16x8 bC[8];
#pragma unroll
    for (int j = 0; j < 8; j++) bC[j] = *(const bf16x8*)bp[j];

    for (int kb = 0; kb < 31; kb++) {        // K = H/32 = 32 steps, 1-step prefetch
        bf16x8 aN = *(const bf16x8*)(ap + (kb + 1) * 32);
        bf16x8 bN[8];
#pragma unroll
        for (int j = 0; j < 8; j++) bN[j] = *(const bf16x8*)(bp[j] + ((kb + 1) << 9));
#pragma unroll
        for (int j = 0; j < 8; j++)
            acc[j] = __builtin_amdgcn_mfma_f32_16x16x32_bf16(aC, bC[j], acc[j], 0, 0, 0);
        aC = aN;
#pragma unroll
        for (int j = 0; j < 8; j++) bC[j] = bN[j];
    }
#pragma unroll
    for (int j = 0; j < 8; j++)
        acc[j] = __builtin_amdgcn_mfma_f32_16x16x32_bf16(aC, bC[j], acc[j], 0, 0, 0);

    // epilogue: C[m=quad*4+r][n=l16]; silu(g)*u*w
#pragma unroll
    for (int r = 0; r < 4; r++) {
        int R = t0 + wv * 16 + quad * 4 + r;
        if (R < n) {
            float w = w_list[e * BS + R];
            size_t rowoff = (size_t)(base + R) * F + f0 + l16;
#pragma unroll
            for (int j = 0; j < 4; j++) {
                float g = acc[j][r], u = acc[j + 4][r];
                float v = (g / (1.f + expf(-g))) * u * w;
                act[rowoff + j * 16] = f2bf(v);
            }
        }
    }
}

// ---- K4: down MFMA, same barrier-free pipeline; N=128 h-cols/block, K=F=512 ----
__global__ __launch_bounds__(256) void down_mfma_kernel(
    const u16* __restrict__ act, const u16* __restrict__ down_f,
    const int* __restrict__ counters, const int* __restrict__ tok_list,
    float* __restrict__ out)
{
    int e = blockIdx.z;
    int n = counters[16 + e];
    int t0 = blockIdx.y * 64;
    if (t0 >= n) return;
    int h0 = blockIdx.x * 128;   // 8 h-groups -> covers H=1024
    int base = 0;
#pragma unroll
    for (int i = 0; i < E; i++) if (i < e) base += counters[16 + i];

    int tid = threadIdx.x;
    int wv = tid >> 6, lane = tid & 63;
    int l16 = lane & 15, quad = lane >> 4;

    int Ra = min(t0 + wv * 16 + l16, n - 1);
    const u16* ap = act + (size_t)(base + Ra) * F + quad * 8;
    const u16* bp[8];
#pragma unroll
    for (int j = 0; j < 8; j++) {
        int nbj = (h0 >> 4) + j;
        bp[j] = down_f + ((size_t)e << 19) + ((size_t)nbj << 13) + (size_t)lane * 8;
    }

    f32x4 acc[8];
#pragma unroll
    for (int j = 0; j < 8; j++) acc[j] = (f32x4){0.f, 0.f, 0.f, 0.f};

    bf16x8 aC = *(const bf16x8*)ap;
    bf16x8 bC[8];
#pragma unroll
    for (int j = 0; j < 8; j++) bC[j] = *(const bf16x8*)bp[j];

    for (int kb = 0; kb < 15; kb++) {        // K = F/32 = 16 steps
        bf16x8 aN = *(const bf16x8*)(ap + (kb + 1) * 32);
        bf16x8 bN[8];
#pragma unroll
        for (int j = 0; j < 8; j++) bN[j] = *(const bf16x8*)(bp[j] + ((kb + 1) << 9));
#pragma unroll
        for (int j = 0; j < 8; j++)
            acc[j] = __builtin_amdgcn_mfma_f32_16x16x32_bf16(aC, bC[j], acc[j], 0, 0, 0);
        aC = aN;
#pragma unroll
        for (int j = 0; j < 8; j++) bC[j] = bN[j];
    }
#pragma unroll
    for (int j = 0; j < 8; j++)
        acc[j] = __builtin_amdgcn_mfma_f32_16x16x32_bf16(aC, bC[j], acc[j], 0, 0, 0);

#pragma unroll
    for (int r = 0; r < 4; r++) {
        int R = t0 + wv * 16 + quad * 4 + r;
        if (R < n) {
            int tok = tok_list[e * BS + R];
            float* orow = out + (size_t)tok * H + h0 + l16;
#pragma unroll
            for (int j = 0; j < 8; j++)
                atomicAdd(&orow[j * 16], acc[j][r]);
        }
    }
}

extern "C" void kernel_launch(void* const* d_in, const int* in_sizes, int n_in,
                              void* d_out, int out_size, void* d_ws, size_t ws_size,
                              hipStream_t stream)
{
    const float* x       = (const float*)d_in[0];
    const float* gate_w  = (const float*)d_in[1];
    const float* gup     = (const float*)d_in[2];
    const float* down    = (const float*)d_in[3];
    const int*   tok_mod = (const int*)d_in[4];
    const int*   exp_mod = (const int*)d_in[5];
    float* out = (float*)d_out;

    char* ws = (char*)d_ws;
    int*    counters = (int*)ws;
    int2*   sel      = (int2*)(ws + 4096);
    float2* wsel     = (float2*)(ws + 20480);
    int*    tok_list = (int*)(ws + 36864);
    float*  w_list   = (float*)(ws + 102400);
    u16*    x_bf     = (u16*)(ws + 167936);
    u16*    gup_f    = (u16*)(ws + 4362240);
    u16*    down_f   = (u16*)(ws + 21139456);
    u16*    act      = (u16*)(ws + 29528064);

    prep_router_kernel<<<3584, 256, 0, stream>>>(gup, down, gup_f, down_f,
                                                 x, gate_w, tok_mod, exp_mod,
                                                 sel, wsel, x_bf, out);
    finalize_kernel<<<1, 1024, 0, stream>>>(exp_mod, counters, sel, wsel, tok_list, w_list);
    gu_mfma_kernel<<<dim3(8, 32, E), 256, 0, stream>>>(x_bf, gup_f, counters, tok_list, w_list, act);
    down_mfma_kernel<<<dim3(8, 32, E), 256, 0, stream>>>(act, down_f, counters, tok_list, out);
}